// Round 4
// baseline (290.833 us; speedup 1.0000x reference)
//
#include <hip/hip_runtime.h>
#include <utility>

// ---------------------------------------------------------------------------
// Compile-time Clebsch-Gordan coefficients (Racah formula), fp64 -> fp32.
// Split into 4 tables (one per l1) to stay under clang's constexpr step limit.
// ---------------------------------------------------------------------------
namespace cg {

constexpr double FACT[14] = {
  1.0, 1.0, 2.0, 6.0, 24.0, 120.0, 720.0, 5040.0, 40320.0, 362880.0,
  3628800.0, 39916800.0, 479001600.0, 6227020800.0
};

constexpr double csqrt(double x){
  double g = x > 1.0 ? x : 1.0;
  for (int i = 0; i < 64; ++i) g = 0.5 * (g + x / g);
  return g;
}
constexpr int cabs_(int x){ return x < 0 ? -x : x; }
constexpr int imax_(int a, int b){ return a > b ? a : b; }
constexpr int imin_(int a, int b){ return a < b ? a : b; }

constexpr double cg_coeff(int j1,int m1,int j2,int m2,int j,int m){
  if (m1 + m2 != m || j < cabs_(j1 - j2) || j > j1 + j2) return 0.0;
  double pre = csqrt((2.0*j + 1.0) * FACT[j1+j2-j] * FACT[j+j1-j2] * FACT[j+j2-j1]
                     / FACT[j1+j2+j+1]);
  pre *= csqrt(FACT[j+m] * FACT[j-m] * FACT[j1+m1] * FACT[j1-m1]
             * FACT[j2+m2] * FACT[j2-m2]);
  double s = 0.0;
  for (int k = 0; k <= j1 + j2 - j; ++k){
    int d2 = j1 - m1 - k, d3 = j2 + m2 - k, d4 = j - j2 + m1 + k, d5 = j - j1 - m2 + k;
    if (d2 < 0 || d3 < 0 || d4 < 0 || d5 < 0) continue;
    double denom = FACT[k] * FACT[j1+j2-j-k] * FACT[d2] * FACT[d3] * FACT[d4] * FACT[d5];
    s += ((k & 1) ? -1.0 : 1.0) / denom;
  }
  return pre * s;
}

struct Tab1 { float c[4][7][7][7]; };  // [l2][l][m1+l1][m2+l2] for fixed l1
constexpr Tab1 make_tab1(int l1){
  Tab1 t{};
  for (int l2 = 0; l2 < 4; ++l2)
    for (int l = 0; l < 7; ++l)
      for (int i1 = 0; i1 < 2*l1 + 1; ++i1)
        for (int i2 = 0; i2 < 2*l2 + 1; ++i2){
          int m1 = i1 - l1, m2 = i2 - l2, m = m1 + m2;
          if (m < -l || m > l) continue;
          t.c[l2][l][i1][i2] = (float)cg_coeff(l1, m1, l2, m2, l, m);
        }
  return t;
}
constexpr Tab1 T0 = make_tab1(0);
constexpr Tab1 T1 = make_tab1(1);
constexpr Tab1 T2 = make_tab1(2);
constexpr Tab1 T3 = make_tab1(3);
constexpr float getc(int l1,int l2,int l,int i1,int i2){
  return l1 == 0 ? T0.c[l2][l][i1][i2]
       : l1 == 1 ? T1.c[l2][l][i1][i2]
       : l1 == 2 ? T2.c[l2][l][i1][i2]
       :           T3.c[l2][l][i1][i2];
}

// Fragment (l1,l2) pair lists in gelib order (l1-major), per output l.
constexpr int NP[7]    = {4, 9, 11, 10, 6, 3, 1};          // tau_l
constexpr int IOFF[4]  = {0, 1, 4, 9};                     // input offset per l (pair units)
constexpr int P1[7][11] = {
  {0,1,2,3,0,0,0,0,0,0,0},
  {0,1,1,1,2,2,2,3,3,0,0},
  {0,1,1,1,2,2,2,2,3,3,3},
  {0,1,1,2,2,2,3,3,3,3,0},
  {1,2,2,3,3,3,0,0,0,0,0},
  {2,3,3,0,0,0,0,0,0,0,0},
  {3,0,0,0,0,0,0,0,0,0,0}
};
constexpr int P2[7][11] = {
  {0,1,2,3,0,0,0,0,0,0,0},
  {1,0,1,2,1,2,3,2,3,0,0},
  {2,1,2,3,0,1,2,3,1,2,3},
  {3,2,3,1,2,3,0,1,2,3,0},
  {3,2,3,1,2,3,0,0,0,0,0},
  {3,2,3,0,0,0,0,0,0,0,0},
  {3,0,0,0,0,0,0,0,0,0,0}
};

// ---- Row table: 49 output rows (l, mi), each 2*NP[l] floats, laid out
// consecutively in the 512-float per-element output. ----
constexpr int ROWN = 49;
struct Rows { int l[ROWN]; int mi[ROWN]; int off[ROWN]; int sz[ROWN]; };
constexpr Rows make_rows(){
  Rows r{}; int idx = 0; int off = 0;
  for (int l = 0; l < 7; ++l)
    for (int mi = 0; mi < 2*l + 1; ++mi){
      r.l[idx] = l; r.mi[idx] = mi; r.off[idx] = off; r.sz[idx] = 2*NP[l];
      off += 2*NP[l]; ++idx;
    }
  return r;
}
constexpr Rows RW = make_rows();

// ---- Item table: every (row, pair) item emits exactly 2 floats (fr,fi) at
// even offset off = RW.off[r] + 2t, so items NEVER straddle a 32-float
// (128 B) boundary. Chunk the 512-float output into 16 chunks of exactly
// 32 floats (= one 128 B line); each chunk is exactly 16 items. Every
// copy-out store is a float4 into a fully-written, 128B-aligned line:
// no partial cache lines -> no DRAM read-modify-write.  [verified R3: -73us]
// ----
constexpr int NCH = 16;        // 16 chunks x 32 floats = 512
constexpr int CW  = 32;        // floats per element per chunk
struct CItems { int r[16]; int t[16]; };
struct AllItems { CItems ch[NCH]; };
constexpr AllItems make_items(){
  AllItems a{};
  int n[NCH] = {};
  for (int r = 0; r < ROWN; ++r){
    int l = RW.l[r];
    for (int t = 0; t < NP[l]; ++t){
      int off = RW.off[r] + 2*t;
      int c = off / CW;
      a.ch[c].r[n[c]] = r; a.ch[c].t[n[c]] = t; ++n[c];
    }
  }
  return a;
}
constexpr AllItems AI = make_items();

} // namespace cg

// ---------------------------------------------------------------------------
// static_for: guarantees every loop index is a compile-time constant
// ---------------------------------------------------------------------------
template<class F, int... Is>
__device__ __forceinline__ void sfor_impl(F&& f, std::integer_sequence<int, Is...>){
  (f(std::integral_constant<int, Is>{}), ...);
}
template<int N, class F>
__device__ __forceinline__ void sfor(F&& f){
  sfor_impl(static_cast<F&&>(f), std::make_integer_sequence<int, N>{});
}

typedef float f32x4 __attribute__((ext_vector_type(4)));

// ---------------------------------------------------------------------------
// Kernel (R4): BARRIER-FREE wave-private staging.
//
// Observation: the staging is wave-private — each wave's 64 lanes compute 64
// elements and copy out exactly those 64 elements. No cross-wave data flow.
// So each wave gets its own double-buffered LDS region and ALL s_barriers are
// deleted. Why this should help:
//   1. No 16x block-wide barrier convergence (waves idled there instead of
//      issuing stores; only 8 waves/CU to cover the gap).
//   2. No global phase lock: barrier-synced waves all store to the same
//      128 B column (addr bits [10:7] == chunk id) simultaneously, GPU-wide.
//      Free-running waves drift apart and spread those bits.
// Wave-internal LDS ordering (write->read, read->next-write WAR) is enforced
// by the compiler's own lgkmcnt insertion — no explicit sync needed.
//
// LDS: lds[wid][parity][32*64] floats = 4 x 2 x 8 KB = 64 KB (static limit).
// Swizzle: value (elem e, float j) at buf[j*64 + (e ^ K(j))], K(j)=4*(j>>2).
//   writes (j const): col = lane ^ K — permutation of 0..63 -> 2 lanes/bank.
//   reads (j=4*c4+i, K=4*c4): bank = ((e0+8kk) ^ 4c4) & 31 — for fixed kk,
//     b0..b1 from e0, b2=e0_2^c4_0, b3=kk_0^c4_1, b4=kk_1^c4_2: exactly 2
//     lanes per bank. Both free. K identical for fr/fi (loc even) and for
//     the 4 dwords of each float4.
//
// Copy-out: e0 = lane>>3, c4 = lane&7; 8 iters of one float4 NT store cover
// 64 elem x 32 floats. Non-temporal: output is write-once/never-read ->
// don't cycle 268 MB of dirty lines through the 32 MB L2.
// ---------------------------------------------------------------------------
__global__ __launch_bounds__(256) void cgprod_kernel(
    const float* __restrict__ x0, const float* __restrict__ x1,
    const float* __restrict__ x2, const float* __restrict__ x3,
    float* __restrict__ out, int B)
{
  constexpr int WBUF = cg::CW * 64;           // 2048 floats per wave buffer
  __shared__ float lds[4][2][WBUF];           // 65536 B == static limit

  const int tid  = threadIdx.x;
  const int wid  = tid >> 6;
  const int lane = tid & 63;
  const int wave_base = blockIdx.x * 256 + 64 * wid;
  const int b  = wave_base + lane;
  const int bc = b < B ? b : B - 1;           // clamp (B%256==0 in practice)
  const bool full = (wave_base + 64 <= B);

  float xr[16], xi[16];  // per-l pair offsets 0,1,4,9 (sizes 1,3,5,7)
  { float2 v = *reinterpret_cast<const float2*>(x0 + (size_t)bc * 2);
    xr[0] = v.x; xi[0] = v.y; }
  { const float2* p = reinterpret_cast<const float2*>(x1 + (size_t)bc * 6);
    sfor<3>([&](auto I){ constexpr int i = decltype(I)::value;
      float2 v = p[i]; xr[1+i] = v.x; xi[1+i] = v.y; }); }
  { const float2* p = reinterpret_cast<const float2*>(x2 + (size_t)bc * 10);
    sfor<5>([&](auto I){ constexpr int i = decltype(I)::value;
      float2 v = p[i]; xr[4+i] = v.x; xi[4+i] = v.y; }); }
  { const float2* p = reinterpret_cast<const float2*>(x3 + (size_t)bc * 14);
    sfor<7>([&](auto I){ constexpr int i = decltype(I)::value;
      float2 v = p[i]; xr[9+i] = v.x; xi[9+i] = v.y; }); }

  const int e0 = lane >> 3;        // element (within wave) in copy-out
  const int c4 = lane & 7;         // float4 index within the 32-float chunk

  sfor<cg::NCH>([&](auto CC){
    constexpr int c = decltype(CC)::value;
    constexpr int G = c * cg::CW;             // global float offset of chunk
    float* buf = &lds[0][0][0] + (wid * 2 + (c & 1)) * WBUF;

    // --- compute this chunk's 16 (fr,fi) items, stage into wave-private LDS ---
    sfor<16>([&](auto IC){
      constexpr int it = decltype(IC)::value;
      constexpr int r  = cg::AI.ch[c].r[it];
      constexpr int t  = cg::AI.ch[c].t[it];
      constexpr int l  = cg::RW.l[r];
      constexpr int m  = cg::RW.mi[r] - l;
      constexpr int l1 = cg::P1[l][t];
      constexpr int l2 = cg::P2[l][t];
      constexpr int loc = (cg::RW.off[r] + 2*t) - G;  // 0..30, even
      constexpr int K   = 4 * (loc >> 2);             // same for loc, loc+1
      constexpr int m1lo = cg::imax_(-l1, m - l2);
      constexpr int m1hi = cg::imin_( l1, m + l2);
      float fr = 0.f, fi = 0.f;
      sfor<m1hi - m1lo + 1>([&](auto KC){
        constexpr int m1 = m1lo + decltype(KC)::value;
        constexpr int m2 = m - m1;
        constexpr float cc = cg::getc(l1, l2, l, m1 + l1, m2 + l2);
        if constexpr (cc != 0.0f){
          constexpr int ia = cg::IOFF[l1] + m1 + l1;
          constexpr int ib = cg::IOFF[l2] + m2 + l2;
          const float ar = xr[ia], ai = xi[ia];
          const float br = xr[ib], bi = xi[ib];
          const float tr = fmaf(-ai, bi, ar * br);  // re(x_l1 * x_l2)
          const float ti = fmaf( ai, br, ar * bi);  // im(x_l1 * x_l2)
          fr = fmaf(cc, tr, fr);
          fi = fmaf(cc, ti, fi);
        }
      });
      const int col = lane ^ K;
      buf[(loc    ) * 64 + col] = fr;
      buf[(loc + 1) * 64 + col] = fi;
    });

    // --- coalesced float4 NT copy-out: 8 iters cover 64 elem x 32 floats ---
    // (compiler inserts the lgkmcnt waits for the write->read dependency and
    //  the read->next-chunk-write WAR; double buffer keeps WAR off the
    //  critical path)
    if (full){
      sfor<8>([&](auto KK){
        constexpr int kk = decltype(KK)::value;
        const int el  = e0 + 8 * kk;
        const int col = el ^ (4 * c4);
        f32x4 v;
        v.x = buf[(4*c4 + 0) * 64 + col];
        v.y = buf[(4*c4 + 1) * 64 + col];
        v.z = buf[(4*c4 + 2) * 64 + col];
        v.w = buf[(4*c4 + 3) * 64 + col];
        __builtin_nontemporal_store(
            v, reinterpret_cast<f32x4*>(out + (size_t)(wave_base + el) * 512 + G + 4*c4));
      });
    } else {
      sfor<8>([&](auto KK){
        constexpr int kk = decltype(KK)::value;
        const int el  = e0 + 8 * kk;
        const int col = el ^ (4 * c4);
        if (wave_base + el < B){
          f32x4 v;
          v.x = buf[(4*c4 + 0) * 64 + col];
          v.y = buf[(4*c4 + 1) * 64 + col];
          v.z = buf[(4*c4 + 2) * 64 + col];
          v.w = buf[(4*c4 + 3) * 64 + col];
          __builtin_nontemporal_store(
              v, reinterpret_cast<f32x4*>(out + (size_t)(wave_base + el) * 512 + G + 4*c4));
        }
      });
    }
  });
}

extern "C" void kernel_launch(void* const* d_in, const int* in_sizes, int n_in,
                              void* d_out, int out_size, void* d_ws, size_t ws_size,
                              hipStream_t stream)
{
  const float* x0 = (const float*)d_in[0];
  const float* x1 = (const float*)d_in[1];
  const float* x2 = (const float*)d_in[2];
  const float* x3 = (const float*)d_in[3];
  float* out = (float*)d_out;

  const int B = in_sizes[0] / 2;  // x0 is (B, 1, 2)
  const int block = 256;
  const int grid = (B + block - 1) / block;
  cgprod_kernel<<<grid, block, 0, stream>>>(x0, x1, x2, x3, out, B);
}